// Round 7
// baseline (840.534 us; speedup 1.0000x reference)
//
#include <hip/hip_runtime.h>

namespace {

typedef unsigned short u16;
typedef __attribute__((__ext_vector_type__(2))) float f32x2;
typedef __attribute__((__ext_vector_type__(4))) float f32x4;

constexpr int Un = 100000;
constexpr int In = 50000;
constexpr int Nn = 150000;
constexpr int D  = 64;
constexpr int Ln = 3;
constexpr int En = 2000000;
constexpr int CHUNK = 1024;
constexpr int NB = (Nn + CHUNK - 1) / CHUNK;  // 147 scan blocks
constexpr int DCAP = 128;                     // degree histogram cap
constexpr int NW = Nn / 8;                    // 18750 waves (8 rows/wave)

__device__ __forceinline__ u16 f2bf(float f) {
    unsigned u = __float_as_uint(f);
    unsigned r = (u + 0x7FFFu + ((u >> 16) & 1u)) >> 16;
    return (u16)r;
}
__device__ __forceinline__ float bflo(unsigned u) {
    return __uint_as_float(u << 16);
}
__device__ __forceinline__ float bfhi(unsigned u) {
    return __uint_as_float(u & 0xFFFF0000u);
}
__device__ __forceinline__ unsigned pack2(float lo, float hi) {
    return (unsigned)f2bf(lo) | ((unsigned)f2bf(hi) << 16);
}

// packed dual-FP32 FMA (CDNA VOP3P)
__device__ __forceinline__ f32x2 pkfma(f32x2 a, f32x2 b, f32x2 c) {
    f32x2 d;
    asm("v_pk_fma_f32 %0, %1, %2, %3" : "=v"(d) : "v"(a), "v"(b), "v"(c));
    return d;
}

// sum across each aligned 8-lane group, pure-VALU DPP (no LDS pipe)
__device__ __forceinline__ float dpp_add8(float x) {
    x += __uint_as_float((unsigned)__builtin_amdgcn_update_dpp(
        0, (int)__float_as_uint(x), 0xB1, 0xF, 0xF, true));
    x += __uint_as_float((unsigned)__builtin_amdgcn_update_dpp(
        0, (int)__float_as_uint(x), 0x4E, 0xF, 0xF, true));
    x += __uint_as_float((unsigned)__builtin_amdgcn_update_dpp(
        0, (int)__float_as_uint(x), 0x141, 0xF, 0xF, true));
    return x;
}

__device__ __forceinline__ void unp8(uint4 q, f32x2* o) {
    o[0].x = bflo(q.x); o[0].y = bfhi(q.x);
    o[1].x = bflo(q.y); o[1].y = bfhi(q.y);
    o[2].x = bflo(q.z); o[2].y = bfhi(q.z);
    o[3].x = bflo(q.w); o[3].y = bfhi(q.w);
}

// count AND record per-edge within-row offset -> fill needs no atomics.
__global__ void count_kernel(const int* __restrict__ rows, int* __restrict__ deg,
                             int* __restrict__ eoff) {
    int e = blockIdx.x * blockDim.x + threadIdx.x;
    if (e < En) eoff[e] = atomicAdd(&deg[rows[e]], 1);
}

__global__ void scan_partial(const int* __restrict__ deg, float* __restrict__ d_is,
                             int* __restrict__ bsum) {
    int tid = threadIdx.x;
    int base = blockIdx.x * CHUNK + tid * 4;
    int s = 0;
#pragma unroll
    for (int i = 0; i < 4; ++i) {
        int idx = base + i;
        if (idx < Nn) {
            int d = deg[idx];
            s += d;
            d_is[idx] = d > 0 ? rsqrtf((float)d) : 0.f;
        }
    }
    __shared__ int sh[256];
    sh[tid] = s;
    __syncthreads();
    for (int o = 128; o > 0; o >>= 1) {
        if (tid < o) sh[tid] += sh[tid + o];
        __syncthreads();
    }
    if (tid == 0) bsum[blockIdx.x] = sh[0];
}

__global__ void scan_top(int* __restrict__ bsum, int* __restrict__ row_ptr) {
    __shared__ int sh[256];
    int tid = threadIdx.x;
    int v = (tid < NB) ? bsum[tid] : 0;
    sh[tid] = v;
    __syncthreads();
    for (int o = 1; o < 256; o <<= 1) {
        int t = (tid >= o) ? sh[tid - o] : 0;
        __syncthreads();
        sh[tid] += t;
        __syncthreads();
    }
    if (tid < NB) bsum[tid] = sh[tid] - v;  // exclusive
    if (tid == 255) row_ptr[Nn] = sh[255];  // == En
}

__global__ void scan_final(const int* __restrict__ deg, const int* __restrict__ bsum,
                           int* __restrict__ row_ptr) {
    int tid = threadIdx.x;
    int base = blockIdx.x * CHUNK + tid * 4;
    int v[4];
    int ts = 0;
#pragma unroll
    for (int i = 0; i < 4; ++i) {
        int idx = base + i;
        v[i] = (idx < Nn) ? deg[idx] : 0;
        ts += v[i];
    }
    __shared__ int sh[256];
    sh[tid] = ts;
    __syncthreads();
    for (int o = 1; o < 256; o <<= 1) {
        int t = (tid >= o) ? sh[tid - o] : 0;
        __syncthreads();
        sh[tid] += t;
        __syncthreads();
    }
    int excl = bsum[blockIdx.x] + sh[tid] - ts;
#pragma unroll
    for (int i = 0; i < 4; ++i) {
        int idx = base + i;
        if (idx < Nn) row_ptr[idx] = excl;
        excl += v[i];
    }
}

// atomic-free scatter; stores BYTE offsets into the 256B/row QA buffer (c*256)
__global__ void fill_kernel(const int* __restrict__ rows, const int* __restrict__ cols,
                            const int* __restrict__ row_ptr, const int* __restrict__ eoff,
                            int* __restrict__ col_off) {
    int e = blockIdx.x * blockDim.x + threadIdx.x;
    if (e >= En) return;
    col_off[row_ptr[rows[e]] + eoff[e]] = cols[e] << 8;
}

// window-sort: counting sort by degree WITHIN each 1024-row block (keeps
// store locality; 8 consecutive sorted rows differ by <=1 in degree).
// srt[p] = {row_ptr[r], row_ptr[r+1], bits(d_is[r]), r}
__global__ void perm_scatter(const int* __restrict__ deg, const int* __restrict__ row_ptr,
                             const float* __restrict__ d_is, int4* __restrict__ srt) {
    __shared__ int lh[DCAP];
    __shared__ int sc[DCAP];
    int tid = threadIdx.x;
    if (tid < DCAP) lh[tid] = 0;
    __syncthreads();
    int base = blockIdx.x * CHUNK + tid * 4;
    int bin[4], rank[4];
#pragma unroll
    for (int i = 0; i < 4; ++i) {
        int idx = base + i;
        if (idx < Nn) {
            bin[i] = min(deg[idx], DCAP - 1);
            rank[i] = atomicAdd(&lh[bin[i]], 1);
        }
    }
    __syncthreads();
    if (tid < DCAP) sc[tid] = lh[tid];
    __syncthreads();
    for (int o = 1; o < DCAP; o <<= 1) {
        int t = (tid < DCAP && tid >= o) ? sc[tid - o] : 0;
        __syncthreads();
        if (tid < DCAP) sc[tid] += t;
        __syncthreads();
    }
    // exclusive base for each bin within this block's window
    if (tid < DCAP) sc[tid] -= lh[tid];
    __syncthreads();
#pragma unroll
    for (int i = 0; i < 4; ++i) {
        int idx = base + i;
        if (idx < Nn) {
            int p = blockIdx.x * CHUNK + sc[bin[i]] + rank[i];
            int4 v;
            v.x = row_ptr[idx];
            v.y = row_ptr[idx + 1];
            v.z = __float_as_int(d_is[idx]);
            v.w = idx;
            srt[p] = v;
        }
    }
}

// emb0 -> acc (f32) and QA0 cur-half (bf16). QA layout: per row 256B =
// [Qn row (128B) | cur row (128B)].
__global__ void init_kernel(const float* __restrict__ ue, const float* __restrict__ ie,
                            float* __restrict__ out, u16* __restrict__ QA0) {
    int i8 = (blockIdx.x * 256 + threadIdx.x) * 8;
    if (i8 >= Nn * D) return;
    const float* src = (i8 < Un * D) ? (ue + i8) : (ie + (i8 - Un * D));
    float4 v0 = ((const float4*)src)[0];
    float4 v1 = ((const float4*)src)[1];
    ((float4*)(out + i8))[0] = v0;
    ((float4*)(out + i8))[1] = v1;
    unsigned r = (unsigned)(i8 >> 6);
    unsigned dpos = (unsigned)(i8 & 63);
    uint4 qa;
    qa.x = pack2(v0.x, v0.y); qa.y = pack2(v0.z, v0.w);
    qa.z = pack2(v1.x, v1.y); qa.w = pack2(v1.z, v1.w);
    *(uint4*)((char*)QA0 + (r << 8) + 128u + dpos * 2u) = qa;
}

// 8 rows per wave, one 8-lane group per row (window-sorted degrees).
// Gathers cur-half of QA + d_is[c] (L2-resident); writes Qn-half + normv.
__global__ __launch_bounds__(256) void spmm_gnn(u16* __restrict__ QA,
                                                const int4* __restrict__ srt,
                                                const int* __restrict__ col_off,
                                                const float* __restrict__ d_is,
                                                float* __restrict__ normv_s) {
    int w = (blockIdx.x * 256 + threadIdx.x) >> 6;
    if (w >= NW) return;
    int lane = threadIdx.x & 63;
    int g = lane >> 3, l = lane & 7;
    unsigned l16 = (unsigned)l * 16u;
    int wb = w * 8 + g;
    int4 q4 = srt[wb];
    int s = q4.x, t = q4.y;
    float dr = __int_as_float(q4.z);
    int r = q4.w;
    const char* pQA = (const char*)QA;
    const char* pd = (const char*)d_is;
    f32x2 z; z.x = 0.f; z.y = 0.f;
    f32x2 a2[4] = {z, z, z, z};
#pragma unroll 4
    for (int j = s; j < t; ++j) {
        unsigned off = (unsigned)col_off[j];           // c*256
        float dv = *(const float*)(pd + (off >> 6));   // d_is[c]
        uint4 q = *(const uint4*)(pQA + (off + 128u + l16));  // cur[c]
        f32x2 x2[4];
        unp8(q, x2);
        f32x2 v2; v2.x = dv; v2.y = dv;
#pragma unroll
        for (int p = 0; p < 4; ++p) a2[p] = pkfma(v2, x2[p], a2[p]);
    }
    float sq = 0.f;
#pragma unroll
    for (int p = 0; p < 4; ++p) {
        sq = fmaf(a2[p].x, a2[p].x, sq);
        sq = fmaf(a2[p].y, a2[p].y, sq);
    }
    sq = dpp_add8(sq);
    float gn = dr * sqrtf(sq);          // ||gnn||  (gnn = dr * a)
    float nrm = fmaxf(gn, 1e-12f);
    float scale = dr / nrm;             // Qn = a * scale
    if (l == 0) normv_s[wb] = nrm;
    unsigned ro = ((unsigned)r << 8) + l16;
    uint4 on;
    on.x = pack2(a2[0].x * scale, a2[0].y * scale);
    on.y = pack2(a2[1].x * scale, a2[1].y * scale);
    on.z = pack2(a2[2].x * scale, a2[2].y * scale);
    on.w = pack2(a2[3].x * scale, a2[3].y * scale);
    *(uint4*)((char*)QA + ro) = on;
}

// merged score+fine, 8 rows/wave. Per edge: TWO ADJACENT 128B lines from the
// QA record (Qn at +0, cur at +128) -> one addr calc, DRAM page locality.
// gnn[r] reconstructed as Qn[r]*normv. cur_new -> cur-half of QA_next.
__global__ __launch_bounds__(256) void score_fine_kernel(const u16* __restrict__ QAc,
                                                         u16* __restrict__ QAn,
                                                         const float* __restrict__ normv_s,
                                                         const int4* __restrict__ srt,
                                                         const int* __restrict__ col_off,
                                                         float* __restrict__ out, int layer) {
    int w = (blockIdx.x * 256 + threadIdx.x) >> 6;
    if (w >= NW) return;
    int lane = threadIdx.x & 63;
    int g = lane >> 3, l = lane & 7;
    unsigned l16 = (unsigned)l * 16u;
    int wb = w * 8 + g;
    int4 q4 = srt[wb];
    int s = q4.x, t = q4.y;
    int r = q4.w;
    float nrm = normv_s[wb];
    const char* pQA = (const char*)QAc;
    unsigned ro = ((unsigned)r << 8) + l16;
    uint4 qbn = *(const uint4*)(pQA + ro);   // Qn[r]
    f32x2 b2[4];
    unp8(qbn, b2);
    f32x2 z; z.x = 0.f; z.y = 0.f;
    f32x2 facc[4] = {z, z, z, z};
    float rowsum = 0.f;
#pragma unroll 4
    for (int j = s; j < t; ++j) {
        unsigned off = (unsigned)col_off[j];
        unsigned vo = off + l16;
        uint4 qx = *(const uint4*)(pQA + vo);          // Qn[c]
        uint4 qy = *(const uint4*)(pQA + vo + 128u);   // cur[c]
        f32x2 x2[4];
        unp8(qx, x2);
        f32x2 d2 = pkfma(b2[0], x2[0], z);
        d2 = pkfma(b2[1], x2[1], d2);
        d2 = pkfma(b2[2], x2[2], d2);
        d2 = pkfma(b2[3], x2[3], d2);
        float d = dpp_add8(d2.x + d2.y);   // group-uniform dot
        float sc = fmaf(d, 0.5f, 0.5f);
        rowsum += sc;
        f32x2 y2[4];
        unp8(qy, y2);
        f32x2 sc2; sc2.x = sc; sc2.y = sc;
#pragma unroll
        for (int p = 0; p < 4; ++p) facc[p] = pkfma(sc2, y2[p], facc[p]);
    }
    float di = rowsum > 0.f ? 1.f / rowsum : 0.f;
    float f[8] = {facc[0].x * di, facc[0].y * di, facc[1].x * di, facc[1].y * di,
                  facc[2].x * di, facc[2].y * di, facc[3].x * di, facc[3].y * di};
    float bb[8] = {b2[0].x, b2[0].y, b2[1].x, b2[1].y,
                   b2[2].x, b2[2].y, b2[3].x, b2[3].y};
    float cn[8];
#pragma unroll
    for (int k = 0; k < 8; ++k) cn[k] = fmaf(bb[k], nrm, f[k]);  // gnn + fine
    uint4 qn;
    qn.x = pack2(cn[0], cn[1]); qn.y = pack2(cn[2], cn[3]);
    qn.z = pack2(cn[4], cn[5]); qn.w = pack2(cn[6], cn[7]);
    *(uint4*)((char*)QAn + ro + 128u) = qn;  // cur_new
    float* op = out + (size_t)r * D + l * 8;
    float4 a0 = ((float4*)op)[0], a1 = ((float4*)op)[1];
    a0.x += cn[0]; a0.y += cn[1]; a0.z += cn[2]; a0.w += cn[3];
    a1.x += cn[4]; a1.y += cn[5]; a1.z += cn[6]; a1.w += cn[7];
    ((float4*)op)[0] = a0;
    ((float4*)op)[1] = a1;
    size_t fo;
    if (r < Un)
        fo = (size_t)Nn * D + (size_t)layer * Un * D + (size_t)r * D + l * 8;
    else
        fo = (size_t)Nn * D + (size_t)Ln * Un * D + (size_t)layer * In * D
             + (size_t)(r - Un) * D + l * 8;
    f32x4 f0, f1;
    f0.x = f[0]; f0.y = f[1]; f0.z = f[2]; f0.w = f[3];
    f1.x = f[4]; f1.y = f[5]; f1.z = f[6]; f1.w = f[7];
    __builtin_nontemporal_store(f0, (f32x4*)(out + fo));
    __builtin_nontemporal_store(f1, (f32x4*)(out + fo) + 1);
}

}  // namespace

extern "C" void kernel_launch(void* const* d_in, const int* in_sizes, int n_in,
                              void* d_out, int out_size, void* d_ws, size_t ws_size,
                              hipStream_t stream) {
    const float* user_emb = (const float*)d_in[0];
    const float* item_emb = (const float*)d_in[1];
    const int* rows = (const int*)d_in[2];
    const int* cols = (const int*)d_in[3];
    float* out = (float*)d_out;

    char* ws = (char*)d_ws;
    size_t off = 0;
    auto alloc = [&](size_t bytes) -> void* {
        void* p = ws + off;
        off += (bytes + 255) & ~size_t(255);
        return p;
    };
    u16*   QA0     = (u16*)  alloc((size_t)Nn * 256);    // 38.4 MB [Qn|cur]
    u16*   QA1     = (u16*)  alloc((size_t)Nn * 256);    // 38.4 MB
    int*   col_off = (int*)  alloc((size_t)(En + 8) * 4);// byte offsets c*256
    int*   deg     = (int*)  alloc((size_t)Nn * 4);
    int*   row_ptr = (int*)  alloc((size_t)(Nn + 1) * 4);
    float* d_is    = (float*)alloc((size_t)Nn * 4);
    float* normv_s = (float*)alloc((size_t)Nn * 4);
    int4*  srt     = (int4*) alloc((size_t)Nn * 16);     // sorted row records
    int*   bsum    = (int*)  alloc(4096);
    // eoff (8 MB) aliases QA1: QA1 first written by score layer 0,
    // strictly after fill_kernel has consumed eoff.
    int*   eoff    = (int*)QA1;
    (void)ws_size; (void)in_sizes; (void)n_in; (void)out_size;

    hipMemsetAsync(deg, 0, (size_t)Nn * 4, stream);

    const int EB = (En + 255) / 256;
    count_kernel<<<EB, 256, 0, stream>>>(rows, deg, eoff);
    scan_partial<<<NB, 256, 0, stream>>>(deg, d_is, bsum);
    scan_top<<<1, 256, 0, stream>>>(bsum, row_ptr);
    scan_final<<<NB, 256, 0, stream>>>(deg, bsum, row_ptr);
    fill_kernel<<<EB, 256, 0, stream>>>(rows, cols, row_ptr, eoff, col_off);
    perm_scatter<<<NB, 256, 0, stream>>>(deg, row_ptr, d_is, srt);
    init_kernel<<<(Nn * D / 8 + 255) / 256, 256, 0, stream>>>(user_emb, item_emb,
                                                              out, QA0);

    const int WB = (NW * 64 + 255) / 256;  // 4688 blocks, 4 waves/block, 8 rows/wave
    u16* Pq = QA0;  // current-layer record [Qn_l | cur_l]
    u16* Nq = QA1;  // next-layer record
    for (int l = 0; l < Ln; ++l) {
        spmm_gnn<<<WB, 256, 0, stream>>>(Pq, srt, col_off, d_is, normv_s);
        score_fine_kernel<<<WB, 256, 0, stream>>>(Pq, Nq, normv_s, srt,
                                                  col_off, out, l);
        u16* tmp = Pq; Pq = Nq; Nq = tmp;
    }
}

// Round 8
// 824.114 us; speedup vs baseline: 1.0199x; 1.0199x over previous
//
#include <hip/hip_runtime.h>

namespace {

typedef unsigned short u16;
typedef __attribute__((__ext_vector_type__(2))) float f32x2;
typedef __attribute__((__ext_vector_type__(4))) float f32x4;

constexpr int Un = 100000;
constexpr int In = 50000;
constexpr int Nn = 150000;
constexpr int D  = 64;
constexpr int Ln = 3;
constexpr int En = 2000000;
constexpr int CHUNK = 1024;
constexpr int NB = (Nn + CHUNK - 1) / CHUNK;  // 147 scan blocks
constexpr int DCAP = 128;                     // degree histogram cap
constexpr int NW = Nn / 8;                    // 18750 waves (8 rows/wave)

__device__ __forceinline__ u16 f2bf(float f) {
    unsigned u = __float_as_uint(f);
    unsigned r = (u + 0x7FFFu + ((u >> 16) & 1u)) >> 16;
    return (u16)r;
}
__device__ __forceinline__ float bflo(unsigned u) {
    return __uint_as_float(u << 16);
}
__device__ __forceinline__ float bfhi(unsigned u) {
    return __uint_as_float(u & 0xFFFF0000u);
}
__device__ __forceinline__ unsigned pack2(float lo, float hi) {
    return (unsigned)f2bf(lo) | ((unsigned)f2bf(hi) << 16);
}

// packed dual-FP32 FMA / ADD (CDNA VOP3P)
__device__ __forceinline__ f32x2 pkfma(f32x2 a, f32x2 b, f32x2 c) {
    f32x2 d;
    asm("v_pk_fma_f32 %0, %1, %2, %3" : "=v"(d) : "v"(a), "v"(b), "v"(c));
    return d;
}
__device__ __forceinline__ f32x2 pkadd(f32x2 a, f32x2 b) {
    f32x2 d;
    asm("v_pk_add_f32 %0, %1, %2" : "=v"(d) : "v"(a), "v"(b));
    return d;
}

// sum across each aligned 8-lane group, pure-VALU DPP (no LDS pipe)
__device__ __forceinline__ float dpp_add8(float x) {
    x += __uint_as_float((unsigned)__builtin_amdgcn_update_dpp(
        0, (int)__float_as_uint(x), 0xB1, 0xF, 0xF, true));
    x += __uint_as_float((unsigned)__builtin_amdgcn_update_dpp(
        0, (int)__float_as_uint(x), 0x4E, 0xF, 0xF, true));
    x += __uint_as_float((unsigned)__builtin_amdgcn_update_dpp(
        0, (int)__float_as_uint(x), 0x141, 0xF, 0xF, true));
    return x;
}

__device__ __forceinline__ void unp8(uint4 q, f32x2* o) {
    o[0].x = bflo(q.x); o[0].y = bfhi(q.x);
    o[1].x = bflo(q.y); o[1].y = bfhi(q.y);
    o[2].x = bflo(q.z); o[2].y = bfhi(q.z);
    o[3].x = bflo(q.w); o[3].y = bfhi(q.w);
}

// count AND record per-edge within-row offset -> fill needs no atomics.
__global__ void count_kernel(const int* __restrict__ rows, int* __restrict__ deg,
                             int* __restrict__ eoff) {
    int e = blockIdx.x * blockDim.x + threadIdx.x;
    if (e < En) eoff[e] = atomicAdd(&deg[rows[e]], 1);
}

__global__ void scan_partial(const int* __restrict__ deg, float* __restrict__ d_is,
                             int* __restrict__ bsum) {
    int tid = threadIdx.x;
    int base = blockIdx.x * CHUNK + tid * 4;
    int s = 0;
#pragma unroll
    for (int i = 0; i < 4; ++i) {
        int idx = base + i;
        if (idx < Nn) {
            int d = deg[idx];
            s += d;
            d_is[idx] = d > 0 ? rsqrtf((float)d) : 0.f;
        }
    }
    __shared__ int sh[256];
    sh[tid] = s;
    __syncthreads();
    for (int o = 128; o > 0; o >>= 1) {
        if (tid < o) sh[tid] += sh[tid + o];
        __syncthreads();
    }
    if (tid == 0) bsum[blockIdx.x] = sh[0];
}

__global__ void scan_top(int* __restrict__ bsum, int* __restrict__ row_ptr) {
    __shared__ int sh[256];
    int tid = threadIdx.x;
    int v = (tid < NB) ? bsum[tid] : 0;
    sh[tid] = v;
    __syncthreads();
    for (int o = 1; o < 256; o <<= 1) {
        int t = (tid >= o) ? sh[tid - o] : 0;
        __syncthreads();
        sh[tid] += t;
        __syncthreads();
    }
    if (tid < NB) bsum[tid] = sh[tid] - v;  // exclusive
    if (tid == 255) row_ptr[Nn] = sh[255];  // == En
}

__global__ void scan_final(const int* __restrict__ deg, const int* __restrict__ bsum,
                           int* __restrict__ row_ptr) {
    int tid = threadIdx.x;
    int base = blockIdx.x * CHUNK + tid * 4;
    int v[4];
    int ts = 0;
#pragma unroll
    for (int i = 0; i < 4; ++i) {
        int idx = base + i;
        v[i] = (idx < Nn) ? deg[idx] : 0;
        ts += v[i];
    }
    __shared__ int sh[256];
    sh[tid] = ts;
    __syncthreads();
    for (int o = 1; o < 256; o <<= 1) {
        int t = (tid >= o) ? sh[tid - o] : 0;
        __syncthreads();
        sh[tid] += t;
        __syncthreads();
    }
    int excl = bsum[blockIdx.x] + sh[tid] - ts;
#pragma unroll
    for (int i = 0; i < 4; ++i) {
        int idx = base + i;
        if (idx < Nn) row_ptr[idx] = excl;
        excl += v[i];
    }
}

// atomic-free scatter; stores BYTE offsets (c * 128, all row buffers 128B/row)
__global__ void fill_kernel(const int* __restrict__ rows, const int* __restrict__ cols,
                            const int* __restrict__ row_ptr, const int* __restrict__ eoff,
                            int* __restrict__ col_off) {
    int e = blockIdx.x * blockDim.x + threadIdx.x;
    if (e >= En) return;
    col_off[row_ptr[rows[e]] + eoff[e]] = cols[e] << 7;
}

// window-sort: counting sort by degree WITHIN each 1024-row block (keeps
// store locality; 8 consecutive sorted rows differ by <=1 in degree).
// srt[p] = {row_ptr[r], row_ptr[r+1], bits(d_is[r]), r}
__global__ void perm_scatter(const int* __restrict__ deg, const int* __restrict__ row_ptr,
                             const float* __restrict__ d_is, int4* __restrict__ srt) {
    __shared__ int lh[DCAP];
    __shared__ int sc[DCAP];
    int tid = threadIdx.x;
    if (tid < DCAP) lh[tid] = 0;
    __syncthreads();
    int base = blockIdx.x * CHUNK + tid * 4;
    int bin[4], rank[4];
#pragma unroll
    for (int i = 0; i < 4; ++i) {
        int idx = base + i;
        if (idx < Nn) {
            bin[i] = min(deg[idx], DCAP - 1);
            rank[i] = atomicAdd(&lh[bin[i]], 1);
        }
    }
    __syncthreads();
    if (tid < DCAP) sc[tid] = lh[tid];
    __syncthreads();
    for (int o = 1; o < DCAP; o <<= 1) {
        int t = (tid < DCAP && tid >= o) ? sc[tid - o] : 0;
        __syncthreads();
        if (tid < DCAP) sc[tid] += t;
        __syncthreads();
    }
    if (tid < DCAP) sc[tid] -= lh[tid];  // exclusive base within window
    __syncthreads();
#pragma unroll
    for (int i = 0; i < 4; ++i) {
        int idx = base + i;
        if (idx < Nn) {
            int p = blockIdx.x * CHUNK + sc[bin[i]] + rank[i];
            int4 v;
            v.x = row_ptr[idx];
            v.y = row_ptr[idx + 1];
            v.z = __float_as_int(d_is[idx]);
            v.w = idx;
            srt[p] = v;
        }
    }
}

// emb0 -> acc (f32), cur0 (bf16), S0 = d_is*emb0 (bf16, prescaled for spmm)
__global__ void init_kernel(const float* __restrict__ ue, const float* __restrict__ ie,
                            const float* __restrict__ d_is,
                            float* __restrict__ out, u16* __restrict__ cur,
                            u16* __restrict__ S) {
    int i8 = (blockIdx.x * 256 + threadIdx.x) * 8;
    if (i8 >= Nn * D) return;
    const float* src = (i8 < Un * D) ? (ue + i8) : (ie + (i8 - Un * D));
    float4 v0 = ((const float4*)src)[0];
    float4 v1 = ((const float4*)src)[1];
    ((float4*)(out + i8))[0] = v0;
    ((float4*)(out + i8))[1] = v1;
    uint4 qc;
    qc.x = pack2(v0.x, v0.y); qc.y = pack2(v0.z, v0.w);
    qc.z = pack2(v1.x, v1.y); qc.w = pack2(v1.z, v1.w);
    *(uint4*)((char*)cur + (size_t)i8 * 2) = qc;
    float ds = d_is[i8 >> 6];
    uint4 qs;
    qs.x = pack2(v0.x * ds, v0.y * ds); qs.y = pack2(v0.z * ds, v0.w * ds);
    qs.z = pack2(v1.x * ds, v1.y * ds); qs.w = pack2(v1.z * ds, v1.w * ds);
    *(uint4*)((char*)S + (size_t)i8 * 2) = qs;
}

// 8 rows per wave, one 8-lane group per row (window-sorted degrees).
// Gathers PRESCALED S rows -> 1 load + pk_add per edge; unroll 8 for MLP.
// Outputs Qn = gnn/||gnn|| (bf16) and normv_s[wb] (sorted order).
__global__ __launch_bounds__(256) void spmm_gnn(const u16* __restrict__ S_,
                                                u16* __restrict__ Qn_,
                                                const int4* __restrict__ srt,
                                                const int* __restrict__ col_off,
                                                float* __restrict__ normv_s) {
    int w = (blockIdx.x * 256 + threadIdx.x) >> 6;
    if (w >= NW) return;
    int lane = threadIdx.x & 63;
    int g = lane >> 3, l = lane & 7;
    unsigned l16 = (unsigned)l * 16u;
    int wb = w * 8 + g;
    int4 q4 = srt[wb];
    int s = q4.x, t = q4.y;
    float dr = __int_as_float(q4.z);
    int r = q4.w;
    const char* pS = (const char*)S_;
    f32x2 z; z.x = 0.f; z.y = 0.f;
    f32x2 a2[4] = {z, z, z, z};
#pragma unroll 8
    for (int j = s; j < t; ++j) {
        unsigned off = (unsigned)col_off[j];
        uint4 q = *(const uint4*)(pS + (off + l16));
        f32x2 x2[4];
        unp8(q, x2);
#pragma unroll
        for (int p = 0; p < 4; ++p) a2[p] = pkadd(a2[p], x2[p]);
    }
    float sq = 0.f;
#pragma unroll
    for (int p = 0; p < 4; ++p) {
        sq = fmaf(a2[p].x, a2[p].x, sq);
        sq = fmaf(a2[p].y, a2[p].y, sq);
    }
    sq = dpp_add8(sq);
    float gn = dr * sqrtf(sq);          // ||gnn||  (gnn = dr * a)
    float nrm = fmaxf(gn, 1e-12f);
    float scale = dr / nrm;             // Qn = a * scale
    if (l == 0) normv_s[wb] = nrm;
    unsigned ro = ((unsigned)r << 7) + l16;
    uint4 on;
    on.x = pack2(a2[0].x * scale, a2[0].y * scale);
    on.y = pack2(a2[1].x * scale, a2[1].y * scale);
    on.z = pack2(a2[2].x * scale, a2[2].y * scale);
    on.w = pack2(a2[3].x * scale, a2[3].y * scale);
    *(uint4*)((char*)Qn_ + ro) = on;
}

// merged score+fine, 8 rows/wave. Dot over pre-normalized Qn: sc = 0.5d+0.5.
// gnn[r] reconstructed as Qn[r]*normv. Writes cur_new, S_next, acc RMW, fine.
__global__ __launch_bounds__(256) void score_fine_kernel(const u16* __restrict__ A_,
                                                         const u16* __restrict__ Qn_,
                                                         u16* __restrict__ C_,
                                                         u16* __restrict__ S_,
                                                         const float* __restrict__ normv_s,
                                                         const int4* __restrict__ srt,
                                                         const int* __restrict__ col_off,
                                                         float* __restrict__ out, int layer) {
    int w = (blockIdx.x * 256 + threadIdx.x) >> 6;
    if (w >= NW) return;
    int lane = threadIdx.x & 63;
    int g = lane >> 3, l = lane & 7;
    unsigned l16 = (unsigned)l * 16u;
    int wb = w * 8 + g;
    int4 q4 = srt[wb];
    int s = q4.x, t = q4.y;
    float dsr = __int_as_float(q4.z);
    int r = q4.w;
    float nrm = normv_s[wb];
    const char* pQn = (const char*)Qn_;
    const char* pA  = (const char*)A_;
    unsigned ro = ((unsigned)r << 7) + l16;
    uint4 qbn = *(const uint4*)(pQn + ro);   // Qn[r]
    f32x2 b2[4];
    unp8(qbn, b2);
    f32x2 z; z.x = 0.f; z.y = 0.f;
    f32x2 facc[4] = {z, z, z, z};
    float rowsum = 0.f;
#pragma unroll 4
    for (int j = s; j < t; ++j) {
        unsigned off = (unsigned)col_off[j];
        unsigned vo = off + l16;
        uint4 qx = *(const uint4*)(pQn + vo);   // Qn[c]
        uint4 qy = *(const uint4*)(pA + vo);    // cur[c]
        f32x2 x2[4];
        unp8(qx, x2);
        f32x2 d2 = pkfma(b2[0], x2[0], z);
        d2 = pkfma(b2[1], x2[1], d2);
        d2 = pkfma(b2[2], x2[2], d2);
        d2 = pkfma(b2[3], x2[3], d2);
        float d = dpp_add8(d2.x + d2.y);   // group-uniform dot
        float sc = fmaf(d, 0.5f, 0.5f);
        rowsum += sc;
        f32x2 y2[4];
        unp8(qy, y2);
        f32x2 sc2; sc2.x = sc; sc2.y = sc;
#pragma unroll
        for (int p = 0; p < 4; ++p) facc[p] = pkfma(sc2, y2[p], facc[p]);
    }
    float di = rowsum > 0.f ? 1.f / rowsum : 0.f;
    float f[8] = {facc[0].x * di, facc[0].y * di, facc[1].x * di, facc[1].y * di,
                  facc[2].x * di, facc[2].y * di, facc[3].x * di, facc[3].y * di};
    float bb[8] = {b2[0].x, b2[0].y, b2[1].x, b2[1].y,
                   b2[2].x, b2[2].y, b2[3].x, b2[3].y};
    float cn[8];
#pragma unroll
    for (int k = 0; k < 8; ++k) cn[k] = fmaf(bb[k], nrm, f[k]);  // gnn + fine
    uint4 qn;
    qn.x = pack2(cn[0], cn[1]); qn.y = pack2(cn[2], cn[3]);
    qn.z = pack2(cn[4], cn[5]); qn.w = pack2(cn[6], cn[7]);
    *(uint4*)((char*)C_ + ro) = qn;
    if (layer != Ln - 1) {  // prescaled cur_new for next layer's spmm
        uint4 qs;
        qs.x = pack2(cn[0] * dsr, cn[1] * dsr);
        qs.y = pack2(cn[2] * dsr, cn[3] * dsr);
        qs.z = pack2(cn[4] * dsr, cn[5] * dsr);
        qs.w = pack2(cn[6] * dsr, cn[7] * dsr);
        *(uint4*)((char*)S_ + ro) = qs;
    }
    float* op = out + (size_t)r * D + l * 8;
    float4 a0 = ((float4*)op)[0], a1 = ((float4*)op)[1];
    a0.x += cn[0]; a0.y += cn[1]; a0.z += cn[2]; a0.w += cn[3];
    a1.x += cn[4]; a1.y += cn[5]; a1.z += cn[6]; a1.w += cn[7];
    ((float4*)op)[0] = a0;
    ((float4*)op)[1] = a1;
    size_t fo;
    if (r < Un)
        fo = (size_t)Nn * D + (size_t)layer * Un * D + (size_t)r * D + l * 8;
    else
        fo = (size_t)Nn * D + (size_t)Ln * Un * D + (size_t)layer * In * D
             + (size_t)(r - Un) * D + l * 8;
    f32x4 f0, f1;
    f0.x = f[0]; f0.y = f[1]; f0.z = f[2]; f0.w = f[3];
    f1.x = f[4]; f1.y = f[5]; f1.z = f[6]; f1.w = f[7];
    __builtin_nontemporal_store(f0, (f32x4*)(out + fo));
    __builtin_nontemporal_store(f1, (f32x4*)(out + fo) + 1);
}

}  // namespace

extern "C" void kernel_launch(void* const* d_in, const int* in_sizes, int n_in,
                              void* d_out, int out_size, void* d_ws, size_t ws_size,
                              hipStream_t stream) {
    const float* user_emb = (const float*)d_in[0];
    const float* item_emb = (const float*)d_in[1];
    const int* rows = (const int*)d_in[2];
    const int* cols = (const int*)d_in[3];
    float* out = (float*)d_out;

    char* ws = (char*)d_ws;
    size_t off = 0;
    auto alloc = [&](size_t bytes) -> void* {
        void* p = ws + off;
        off += (bytes + 255) & ~size_t(255);
        return p;
    };
    u16*   buf0    = (u16*)  alloc((size_t)Nn * D * 2);   // cur (plain)
    u16*   buf1    = (u16*)  alloc((size_t)Nn * D * 2);   // cur_new (plain)
    u16*   buf2    = (u16*)  alloc((size_t)Nn * D * 2);   // Qn: normalized gnn
    u16*   buf3    = (u16*)  alloc((size_t)Nn * D * 2);   // S: prescaled cur
    int*   col_off = (int*)  alloc((size_t)(En + 8) * 4); // byte offsets c*128
    int*   deg     = (int*)  alloc((size_t)Nn * 4);
    int*   row_ptr = (int*)  alloc((size_t)(Nn + 1) * 4);
    float* d_is    = (float*)alloc((size_t)Nn * 4);
    float* normv_s = (float*)alloc((size_t)Nn * 4);
    int4*  srt     = (int4*) alloc((size_t)Nn * 16);      // sorted row records
    int*   bsum    = (int*)  alloc(4096);
    // eoff (8 MB) aliases buf2 (Qn): Qn first written by spmm_gnn layer 0,
    // strictly after fill_kernel has consumed eoff.
    int*   eoff    = (int*)buf2;
    (void)ws_size; (void)in_sizes; (void)n_in; (void)out_size;

    hipMemsetAsync(deg, 0, (size_t)Nn * 4, stream);

    const int EB = (En + 255) / 256;
    count_kernel<<<EB, 256, 0, stream>>>(rows, deg, eoff);
    scan_partial<<<NB, 256, 0, stream>>>(deg, d_is, bsum);
    scan_top<<<1, 256, 0, stream>>>(bsum, row_ptr);
    scan_final<<<NB, 256, 0, stream>>>(deg, bsum, row_ptr);
    fill_kernel<<<EB, 256, 0, stream>>>(rows, cols, row_ptr, eoff, col_off);
    perm_scatter<<<NB, 256, 0, stream>>>(deg, row_ptr, d_is, srt);
    // init after scan_partial (needs d_is for the prescaled S0)
    init_kernel<<<(Nn * D / 8 + 255) / 256, 256, 0, stream>>>(user_emb, item_emb, d_is,
                                                              out, buf0, buf3);

    const int WB = (NW * 64 + 255) / 256;  // 4688 blocks, 4 waves/block, 8 rows/wave
    u16* P = buf0;  // cur (plain)
    u16* R = buf1;  // cur_new (plain)
    u16* Qn = buf2;
    u16* S  = buf3; // prescaled cur for spmm (rewritten by score each layer)
    for (int l = 0; l < Ln; ++l) {
        spmm_gnn<<<WB, 256, 0, stream>>>(S, Qn, srt, col_off, normv_s);
        score_fine_kernel<<<WB, 256, 0, stream>>>(P, Qn, R, S, normv_s, srt,
                                                  col_off, out, l);
        u16* tmp = P; P = R; R = tmp;  // cur_new becomes cur
    }
}

// Round 9
// 763.796 us; speedup vs baseline: 1.1005x; 1.0790x over previous
//
#include <hip/hip_runtime.h>

namespace {

typedef unsigned short u16;
typedef __attribute__((__ext_vector_type__(2))) float f32x2;
typedef __attribute__((__ext_vector_type__(4))) float f32x4;

constexpr int Un = 100000;
constexpr int In = 50000;
constexpr int Nn = 150000;
constexpr int D  = 64;
constexpr int Ln = 3;
constexpr int En = 2000000;
constexpr int CHUNK = 1024;
constexpr int NB = (Nn + CHUNK - 1) / CHUNK;  // 147 scan blocks
constexpr int DSTR = 8;                       // deg counter stride (32B padding)

__device__ __forceinline__ u16 f2bf(float f) {
    unsigned u = __float_as_uint(f);
    unsigned r = (u + 0x7FFFu + ((u >> 16) & 1u)) >> 16;
    return (u16)r;
}
__device__ __forceinline__ float bflo(unsigned u) {
    return __uint_as_float(u << 16);
}
__device__ __forceinline__ float bfhi(unsigned u) {
    return __uint_as_float(u & 0xFFFF0000u);
}
__device__ __forceinline__ unsigned pack2(float lo, float hi) {
    return (unsigned)f2bf(lo) | ((unsigned)f2bf(hi) << 16);
}

// packed dual-FP32 FMA / ADD (CDNA VOP3P)
__device__ __forceinline__ f32x2 pkfma(f32x2 a, f32x2 b, f32x2 c) {
    f32x2 d;
    asm("v_pk_fma_f32 %0, %1, %2, %3" : "=v"(d) : "v"(a), "v"(b), "v"(c));
    return d;
}
__device__ __forceinline__ f32x2 pkadd(f32x2 a, f32x2 b) {
    f32x2 d;
    asm("v_pk_add_f32 %0, %1, %2" : "=v"(d) : "v"(a), "v"(b));
    return d;
}

// sum across each aligned 8-lane group, pure-VALU DPP (no LDS pipe)
__device__ __forceinline__ float dpp_add8(float x) {
    x += __uint_as_float((unsigned)__builtin_amdgcn_update_dpp(
        0, (int)__float_as_uint(x), 0xB1, 0xF, 0xF, true));
    x += __uint_as_float((unsigned)__builtin_amdgcn_update_dpp(
        0, (int)__float_as_uint(x), 0x4E, 0xF, 0xF, true));
    x += __uint_as_float((unsigned)__builtin_amdgcn_update_dpp(
        0, (int)__float_as_uint(x), 0x141, 0xF, 0xF, true));
    return x;
}

__device__ __forceinline__ void unp8(uint4 q, f32x2* o) {
    o[0].x = bflo(q.x); o[0].y = bfhi(q.x);
    o[1].x = bflo(q.y); o[1].y = bfhi(q.y);
    o[2].x = bflo(q.z); o[2].y = bfhi(q.z);
    o[3].x = bflo(q.w); o[3].y = bfhi(q.w);
}

// count into PADDED counters (32B apart -> 8x less line contention on the
// 2M device-scope atomic-with-return ops); eoff = within-row rank.
__global__ void count_kernel(const int* __restrict__ rows, int* __restrict__ deg8,
                             int* __restrict__ eoff) {
    int e = blockIdx.x * blockDim.x + threadIdx.x;
    if (e < En) eoff[e] = atomicAdd(&deg8[(size_t)rows[e] * DSTR], 1);
}

__global__ void scan_partial(const int* __restrict__ deg8, float* __restrict__ d_is,
                             int* __restrict__ bsum) {
    int tid = threadIdx.x;
    int base = blockIdx.x * CHUNK + tid * 4;
    int s = 0;
#pragma unroll
    for (int i = 0; i < 4; ++i) {
        int idx = base + i;
        if (idx < Nn) {
            int d = deg8[(size_t)idx * DSTR];
            s += d;
            d_is[idx] = d > 0 ? rsqrtf((float)d) : 0.f;
        }
    }
    __shared__ int sh[256];
    sh[tid] = s;
    __syncthreads();
    for (int o = 128; o > 0; o >>= 1) {
        if (tid < o) sh[tid] += sh[tid + o];
        __syncthreads();
    }
    if (tid == 0) bsum[blockIdx.x] = sh[0];
}

__global__ void scan_top(int* __restrict__ bsum, int* __restrict__ row_ptr) {
    __shared__ int sh[256];
    int tid = threadIdx.x;
    int v = (tid < NB) ? bsum[tid] : 0;
    sh[tid] = v;
    __syncthreads();
    for (int o = 1; o < 256; o <<= 1) {
        int t = (tid >= o) ? sh[tid - o] : 0;
        __syncthreads();
        sh[tid] += t;
        __syncthreads();
    }
    if (tid < NB) bsum[tid] = sh[tid] - v;  // exclusive
    if (tid == 255) row_ptr[Nn] = sh[255];  // == En
}

__global__ void scan_final(const int* __restrict__ deg8, const int* __restrict__ bsum,
                           int* __restrict__ row_ptr) {
    int tid = threadIdx.x;
    int base = blockIdx.x * CHUNK + tid * 4;
    int v[4];
    int ts = 0;
#pragma unroll
    for (int i = 0; i < 4; ++i) {
        int idx = base + i;
        v[i] = (idx < Nn) ? deg8[(size_t)idx * DSTR] : 0;
        ts += v[i];
    }
    __shared__ int sh[256];
    sh[tid] = ts;
    __syncthreads();
    for (int o = 1; o < 256; o <<= 1) {
        int t = (tid >= o) ? sh[tid - o] : 0;
        __syncthreads();
        sh[tid] += t;
        __syncthreads();
    }
    int excl = bsum[blockIdx.x] + sh[tid] - ts;
#pragma unroll
    for (int i = 0; i < 4; ++i) {
        int idx = base + i;
        if (idx < Nn) row_ptr[idx] = excl;
        excl += v[i];
    }
}

// atomic-free scatter; stores BYTE offsets (c * 128, all row buffers 128B/row)
__global__ void fill_kernel(const int* __restrict__ rows, const int* __restrict__ cols,
                            const int* __restrict__ row_ptr, const int* __restrict__ eoff,
                            int* __restrict__ col_off) {
    int e = blockIdx.x * blockDim.x + threadIdx.x;
    if (e >= En) return;
    col_off[row_ptr[rows[e]] + eoff[e]] = cols[e] << 7;
}

// emb0 -> cur0 (bf16) and S0 = d_is*emb0 (bf16). No acc write (final_sum does it).
__global__ void init_kernel(const float* __restrict__ ue, const float* __restrict__ ie,
                            const float* __restrict__ d_is,
                            u16* __restrict__ cur, u16* __restrict__ S) {
    int i8 = (blockIdx.x * 256 + threadIdx.x) * 8;
    if (i8 >= Nn * D) return;
    const float* src = (i8 < Un * D) ? (ue + i8) : (ie + (i8 - Un * D));
    float4 v0 = ((const float4*)src)[0];
    float4 v1 = ((const float4*)src)[1];
    uint4 qc;
    qc.x = pack2(v0.x, v0.y); qc.y = pack2(v0.z, v0.w);
    qc.z = pack2(v1.x, v1.y); qc.w = pack2(v1.z, v1.w);
    *(uint4*)((char*)cur + (size_t)i8 * 2) = qc;
    float ds = d_is[i8 >> 6];
    uint4 qs;
    qs.x = pack2(v0.x * ds, v0.y * ds); qs.y = pack2(v0.z * ds, v0.w * ds);
    qs.z = pack2(v1.x * ds, v1.y * ds); qs.w = pack2(v1.z * ds, v1.w * ds);
    *(uint4*)((char*)S + (size_t)i8 * 2) = qs;
}

// wave per row; 8 edge-groups of 8 lanes; lane holds dims 8l..8l+7.
// Gathers PRESCALED S rows -> 1 load + pk_add per edge.
// Outputs Qn = gnn/||gnn|| (bf16) and normv[r] = max(||gnn||, 1e-12).
__global__ __launch_bounds__(256) void spmm_gnn(const u16* __restrict__ S_,
                                                u16* __restrict__ Qn_,
                                                const int* __restrict__ row_ptr,
                                                const int* __restrict__ col_off,
                                                const float* __restrict__ d_is,
                                                float* __restrict__ normv) {
    int r = (blockIdx.x * 256 + threadIdx.x) >> 6;
    if (r >= Nn) return;
    int lane = threadIdx.x & 63;
    int g = lane >> 3, l = lane & 7;
    unsigned l16 = (unsigned)l * 16u;
    const char* pS = (const char*)S_;
    int s = row_ptr[r], t = row_ptr[r + 1];
    float dr = d_is[r];
    f32x2 z; z.x = 0.f; z.y = 0.f;
    f32x2 a2[4] = {z, z, z, z};
    int deg = t - s;
    int nfull = deg >> 3;
    int rem = deg & 7;
    int jb = s + g;
#pragma unroll 2
    for (int i = 0; i < nfull; ++i) {
        unsigned off = (unsigned)col_off[jb + i * 8];
        uint4 q = *(const uint4*)(pS + (off + l16));
        f32x2 x2[4];
        unp8(q, x2);
#pragma unroll
        for (int p = 0; p < 4; ++p) a2[p] = pkadd(a2[p], x2[p]);
    }
    if (g < rem) {  // group-uniform branch: invalid groups skip the load
        unsigned off = (unsigned)col_off[jb + nfull * 8];
        uint4 q = *(const uint4*)(pS + (off + l16));
        f32x2 x2[4];
        unp8(q, x2);
#pragma unroll
        for (int p = 0; p < 4; ++p) a2[p] = pkadd(a2[p], x2[p]);
    }
    float a[8] = {a2[0].x, a2[0].y, a2[1].x, a2[1].y,
                  a2[2].x, a2[2].y, a2[3].x, a2[3].y};
#pragma unroll
    for (int k = 0; k < 8; ++k) {
        a[k] += __shfl_xor(a[k], 8);
        a[k] += __shfl_xor(a[k], 16);
        a[k] += __shfl_xor(a[k], 32);
    }
    float sq = 0.f;
#pragma unroll
    for (int k = 0; k < 8; ++k) sq = fmaf(a[k], a[k], sq);
    sq = dpp_add8(sq);
    float gn = dr * sqrtf(sq);          // ||gnn||  (gnn = dr * a)
    float nrm = fmaxf(gn, 1e-12f);
    float scale = dr / nrm;             // Qn = a * scale
    if (lane == 8) normv[r] = nrm;      // g1 lane 0
    if (g == 0) {
        unsigned ro = ((unsigned)r << 7) + l16;
        uint4 on;
        on.x = pack2(a[0] * scale, a[1] * scale);
        on.y = pack2(a[2] * scale, a[3] * scale);
        on.z = pack2(a[4] * scale, a[5] * scale);
        on.w = pack2(a[6] * scale, a[7] * scale);
        *(uint4*)((char*)Qn_ + ro) = on;
    }
}

// merged score+fine. Dot over pre-normalized Qn: sc = 0.5d+0.5.
// gnn[r] reconstructed as Qn[r]*normv. After the butterfly, ALL lanes hold
// the reduced values -> epilogue stores distributed: g0=C, g1=S, g2/g3=fine.
// NO acc RMW (final_sum kernel handles acc).
__global__ __launch_bounds__(256) void score_fine_kernel(const u16* __restrict__ A_,
                                                         const u16* __restrict__ Qn_,
                                                         u16* __restrict__ C_,
                                                         u16* __restrict__ S_,
                                                         const float* __restrict__ normv,
                                                         const float* __restrict__ d_is,
                                                         const int* __restrict__ row_ptr,
                                                         const int* __restrict__ col_off,
                                                         float* __restrict__ out, int layer) {
    int r = (blockIdx.x * 256 + threadIdx.x) >> 6;
    if (r >= Nn) return;
    int lane = threadIdx.x & 63;
    int g = lane >> 3, l = lane & 7;
    unsigned l16 = (unsigned)l * 16u;
    const char* pQn = (const char*)Qn_;
    const char* pA  = (const char*)A_;
    int s = row_ptr[r], t = row_ptr[r + 1];
    float dsr = d_is[r];
    float nrm = normv[r];
    unsigned ro = ((unsigned)r << 7) + l16;
    uint4 qbn = *(const uint4*)(pQn + ro);   // Qn[r] (all lanes)
    f32x2 b2[4];
    unp8(qbn, b2);
    f32x2 z; z.x = 0.f; z.y = 0.f;
    f32x2 facc[4] = {z, z, z, z};
    float rowsum = 0.f;
    int deg = t - s;
    int nfull = deg >> 3;
    int rem = deg & 7;
    int jb = s + g;
#pragma unroll 2
    for (int i = 0; i < nfull; ++i) {
        unsigned off = (unsigned)col_off[jb + i * 8];
        unsigned vo = off + l16;
        uint4 qx = *(const uint4*)(pQn + vo);   // Qn[c]
        uint4 qy = *(const uint4*)(pA + vo);    // cur[c]
        f32x2 x2[4];
        unp8(qx, x2);
        f32x2 d2 = pkfma(b2[0], x2[0], z);
        d2 = pkfma(b2[1], x2[1], d2);
        d2 = pkfma(b2[2], x2[2], d2);
        d2 = pkfma(b2[3], x2[3], d2);
        float d = dpp_add8(d2.x + d2.y);   // group-uniform dot
        float sc = fmaf(d, 0.5f, 0.5f);
        rowsum += sc;
        f32x2 y2[4];
        unp8(qy, y2);
        f32x2 sc2; sc2.x = sc; sc2.y = sc;
#pragma unroll
        for (int p = 0; p < 4; ++p) facc[p] = pkfma(sc2, y2[p], facc[p]);
    }
    if (g < rem) {  // group-uniform: invalid groups skip loads entirely
        unsigned off = (unsigned)col_off[jb + nfull * 8];
        unsigned vo = off + l16;
        uint4 qx = *(const uint4*)(pQn + vo);
        uint4 qy = *(const uint4*)(pA + vo);
        f32x2 x2[4];
        unp8(qx, x2);
        f32x2 d2 = pkfma(b2[0], x2[0], z);
        d2 = pkfma(b2[1], x2[1], d2);
        d2 = pkfma(b2[2], x2[2], d2);
        d2 = pkfma(b2[3], x2[3], d2);
        float d = dpp_add8(d2.x + d2.y);
        float sc = fmaf(d, 0.5f, 0.5f);
        rowsum += sc;
        f32x2 y2[4];
        unp8(qy, y2);
        f32x2 sc2; sc2.x = sc; sc2.y = sc;
#pragma unroll
        for (int p = 0; p < 4; ++p) facc[p] = pkfma(sc2, y2[p], facc[p]);
    }
    float f[8] = {facc[0].x, facc[0].y, facc[1].x, facc[1].y,
                  facc[2].x, facc[2].y, facc[3].x, facc[3].y};
    rowsum += __shfl_xor(rowsum, 8);
    rowsum += __shfl_xor(rowsum, 16);
    rowsum += __shfl_xor(rowsum, 32);
#pragma unroll
    for (int k = 0; k < 8; ++k) {
        f[k] += __shfl_xor(f[k], 8);
        f[k] += __shfl_xor(f[k], 16);
        f[k] += __shfl_xor(f[k], 32);
    }
    float di = rowsum > 0.f ? 1.f / rowsum : 0.f;
#pragma unroll
    for (int k = 0; k < 8; ++k) f[k] *= di;
    float bb[8] = {b2[0].x, b2[0].y, b2[1].x, b2[1].y,
                   b2[2].x, b2[2].y, b2[3].x, b2[3].y};
    float cn[8];
#pragma unroll
    for (int k = 0; k < 8; ++k) cn[k] = fmaf(bb[k], nrm, f[k]);  // gnn + fine
    if (g == 0) {
        uint4 qn;
        qn.x = pack2(cn[0], cn[1]); qn.y = pack2(cn[2], cn[3]);
        qn.z = pack2(cn[4], cn[5]); qn.w = pack2(cn[6], cn[7]);
        *(uint4*)((char*)C_ + ro) = qn;
    }
    if (g == 1 && layer != Ln - 1) {  // prescaled cur_new for next spmm
        uint4 qs;
        qs.x = pack2(cn[0] * dsr, cn[1] * dsr);
        qs.y = pack2(cn[2] * dsr, cn[3] * dsr);
        qs.z = pack2(cn[4] * dsr, cn[5] * dsr);
        qs.w = pack2(cn[6] * dsr, cn[7] * dsr);
        *(uint4*)((char*)S_ + ro) = qs;
    }
    if (g >= 2 && g <= 3) {
        size_t fo;
        if (r < Un)
            fo = (size_t)Nn * D + (size_t)layer * Un * D + (size_t)r * D + l * 8;
        else
            fo = (size_t)Nn * D + (size_t)Ln * Un * D + (size_t)layer * In * D
                 + (size_t)(r - Un) * D + l * 8;
        if (g == 2) {
            f32x4 f0; f0.x = f[0]; f0.y = f[1]; f0.z = f[2]; f0.w = f[3];
            __builtin_nontemporal_store(f0, (f32x4*)(out + fo));
        } else {
            f32x4 f1; f1.x = f[4]; f1.y = f[5]; f1.z = f[6]; f1.w = f[7];
            __builtin_nontemporal_store(f1, (f32x4*)(out + fo) + 1);
        }
    }
}

// acc = emb0 (f32, exact) + cur1 + cur2 + cur3 (bf16) -> out[0 : Nn*D]
__global__ void final_sum(const float* __restrict__ ue, const float* __restrict__ ie,
                          const u16* __restrict__ c1, const u16* __restrict__ c2,
                          const u16* __restrict__ c3, float* __restrict__ out) {
    int i8 = (blockIdx.x * 256 + threadIdx.x) * 8;
    if (i8 >= Nn * D) return;
    const float* src = (i8 < Un * D) ? (ue + i8) : (ie + (i8 - Un * D));
    float4 v0 = ((const float4*)src)[0];
    float4 v1 = ((const float4*)src)[1];
    uint4 q1 = *(const uint4*)((const char*)c1 + (size_t)i8 * 2);
    uint4 q2 = *(const uint4*)((const char*)c2 + (size_t)i8 * 2);
    uint4 q3 = *(const uint4*)((const char*)c3 + (size_t)i8 * 2);
    float o[8] = {v0.x, v0.y, v0.z, v0.w, v1.x, v1.y, v1.z, v1.w};
    f32x2 t1[4], t2[4], t3[4];
    unp8(q1, t1); unp8(q2, t2); unp8(q3, t3);
#pragma unroll
    for (int p = 0; p < 4; ++p) {
        o[2 * p]     = ((o[2 * p]     + t1[p].x) + t2[p].x) + t3[p].x;
        o[2 * p + 1] = ((o[2 * p + 1] + t1[p].y) + t2[p].y) + t3[p].y;
    }
    float4 w0, w1;
    w0.x = o[0]; w0.y = o[1]; w0.z = o[2]; w0.w = o[3];
    w1.x = o[4]; w1.y = o[5]; w1.z = o[6]; w1.w = o[7];
    ((float4*)(out + i8))[0] = w0;
    ((float4*)(out + i8))[1] = w1;
}

}  // namespace

extern "C" void kernel_launch(void* const* d_in, const int* in_sizes, int n_in,
                              void* d_out, int out_size, void* d_ws, size_t ws_size,
                              hipStream_t stream) {
    const float* user_emb = (const float*)d_in[0];
    const float* item_emb = (const float*)d_in[1];
    const int* rows = (const int*)d_in[2];
    const int* cols = (const int*)d_in[3];
    float* out = (float*)d_out;

    char* ws = (char*)d_ws;
    size_t off = 0;
    auto alloc = [&](size_t bytes) -> void* {
        void* p = ws + off;
        off += (bytes + 255) & ~size_t(255);
        return p;
    };
    u16*   bufA    = (u16*)  alloc((size_t)Nn * D * 2);   // cur0, later cur3
    u16*   bufB    = (u16*)  alloc((size_t)Nn * D * 2);   // cur1
    u16*   bufC    = (u16*)  alloc((size_t)Nn * D * 2);   // cur2
    u16*   Qn      = (u16*)  alloc((size_t)Nn * D * 2);   // normalized gnn
    u16*   S       = (u16*)  alloc((size_t)Nn * D * 2);   // prescaled cur
    int*   col_off = (int*)  alloc((size_t)(En + 8) * 4); // byte offsets c*128
    int*   deg8    = (int*)  alloc((size_t)Nn * DSTR * 4);// padded counters
    int*   row_ptr = (int*)  alloc((size_t)(Nn + 1) * 4);
    float* d_is    = (float*)alloc((size_t)Nn * 4);
    float* normv   = (float*)alloc((size_t)Nn * 4);
    int*   bsum    = (int*)  alloc(4096);
    // eoff (8 MB) aliases Qn: Qn first written by spmm_gnn layer 0,
    // strictly after fill_kernel has consumed eoff.
    int*   eoff    = (int*)Qn;
    (void)ws_size; (void)in_sizes; (void)n_in; (void)out_size;

    hipMemsetAsync(deg8, 0, (size_t)Nn * DSTR * 4, stream);

    const int EB = (En + 255) / 256;
    count_kernel<<<EB, 256, 0, stream>>>(rows, deg8, eoff);
    scan_partial<<<NB, 256, 0, stream>>>(deg8, d_is, bsum);
    scan_top<<<1, 256, 0, stream>>>(bsum, row_ptr);
    scan_final<<<NB, 256, 0, stream>>>(deg8, bsum, row_ptr);
    fill_kernel<<<EB, 256, 0, stream>>>(rows, cols, row_ptr, eoff, col_off);
    // init after scan_partial (needs d_is for the prescaled S0)
    init_kernel<<<(Nn * D / 8 + 255) / 256, 256, 0, stream>>>(user_emb, item_emb, d_is,
                                                              bufA, S);

    const int RB = Nn / 4;  // 37500 blocks, 4 waves/block, 1 wave/row
    // layer chain: cur0(bufA) -> cur1(bufB) -> cur2(bufC) -> cur3(bufA)
    u16* Pl[4] = {bufA, bufB, bufC, bufA};
    for (int l = 0; l < Ln; ++l) {
        spmm_gnn<<<RB, 256, 0, stream>>>(S, Qn, row_ptr, col_off, d_is, normv);
        score_fine_kernel<<<RB, 256, 0, stream>>>(Pl[l], Qn, Pl[l + 1], S, normv,
                                                  d_is, row_ptr, col_off, out, l);
    }
    final_sum<<<(Nn * D / 8 + 255) / 256, 256, 0, stream>>>(user_emb, item_emb,
                                                            bufB, bufC, bufA, out);
}